// Round 2
// baseline (5817.675 us; speedup 1.0000x reference)
//
#include <hip/hip_runtime.h>

#define EMB 128

__global__ void k_fill1(float* p, int n) {
    int i = blockIdx.x * blockDim.x + threadIdx.x;
    if (i < n) p[i] = 1.0f;
}

__global__ void k_deg_count(const int* __restrict__ dst, float* deg, int E) {
    int e = blockIdx.x * blockDim.x + threadIdx.x;
    if (e < E) atomicAdd(&deg[dst[e]], 1.0f);
}

__global__ void k_rsqrt(float* p, int n) {
    int i = blockIdx.x * blockDim.x + threadIdx.x;
    if (i < n) p[i] = rsqrtf(p[i]);
}

// Y[n][:] = (X[n][:] @ W) * dis[n];  W is f32 [128x128] staged to LDS.
// NOTE: no __restrict__ on X/Y — the layer-2 call runs in-place (X == Y),
// which is safe because each thread reads only its own row fully (into acc)
// before writing that row.
__global__ __launch_bounds__(256) void k_gemm_scale(
    const float* X, const float* __restrict__ W,
    const float* __restrict__ dis, float* Y, int N)
{
    __shared__ float Ws[EMB * EMB];   // 64 KB
    for (int i = threadIdx.x; i < EMB * EMB; i += 256) Ws[i] = W[i];
    __syncthreads();
    int n = blockIdx.x * 256 + threadIdx.x;
    if (n >= N) return;

    float acc[EMB];
#pragma unroll
    for (int j = 0; j < EMB; ++j) acc[j] = 0.0f;

#pragma unroll 1
    for (int k0 = 0; k0 < EMB; k0 += 8) {
        const float4* xp = (const float4*)(X + (size_t)n * EMB + k0);
        float4 u0 = xp[0], u1 = xp[1];
        float a[8] = { u0.x, u0.y, u0.z, u0.w, u1.x, u1.y, u1.z, u1.w };
#pragma unroll
        for (int kk = 0; kk < 8; ++kk) {
            const float* wr = &Ws[(k0 + kk) * EMB];
#pragma unroll
            for (int j = 0; j < EMB; j += 4) {
                float4 w = *(const float4*)(wr + j);
                acc[j+0] += a[kk] * w.x;
                acc[j+1] += a[kk] * w.y;
                acc[j+2] += a[kk] * w.z;
                acc[j+3] += a[kk] * w.w;
            }
        }
    }

    float dv = dis[n];
    float* yr = Y + (size_t)n * EMB;
#pragma unroll
    for (int j = 0; j < EMB; j += 4) {
        float4 o = { acc[j]*dv, acc[j+1]*dv, acc[j+2]*dv, acc[j+3]*dv };
        *(float4*)(yr + j) = o;
    }
}

// 32 lanes per edge: Acc[dst][j..j+3] += Y[src][j..j+3]
__global__ __launch_bounds__(256) void k_scatter(
    const int* __restrict__ src, const int* __restrict__ dst,
    const float* __restrict__ Y, float* __restrict__ Acc, int E)
{
    long long t = (long long)blockIdx.x * 256 + threadIdx.x;
    int e = (int)(t >> 5);
    if (e >= E) return;
    int lane = ((int)t & 31) * 4;
    int s = src[e], d = dst[e];
    const float4 v = *(const float4*)(Y + (size_t)s * EMB + lane);
    float* a = Acc + (size_t)d * EMB + lane;
    atomicAdd(a + 0, v.x);
    atomicAdd(a + 1, v.y);
    atomicAdd(a + 2, v.z);
    atomicAdd(a + 3, v.w);
}

// Out[n][j] = act(dis[n]*(Acc[n][j] + Yin[n][j]) + b[j])
// No __restrict__: calls run in-place (Out aliases Acc or Yin elementwise).
template <bool RELU>
__global__ __launch_bounds__(256) void k_finalize(
    const float* Acc, const float* Yin, float* Out,
    const float* __restrict__ bias, const float* __restrict__ dis, int N)
{
    long long t = (long long)blockIdx.x * 256 + threadIdx.x;
    if (t >= (long long)N * 32) return;
    int n = (int)(t >> 5);
    int j = ((int)t & 31) * 4;
    float dv = dis[n];
    float4 a = *(const float4*)(Acc + (size_t)n * EMB + j);
    float4 y = *(const float4*)(Yin + (size_t)n * EMB + j);
    float4 b = *(const float4*)(bias + j);
    float o0 = dv * (a.x + y.x) + b.x;
    float o1 = dv * (a.y + y.y) + b.y;
    float o2 = dv * (a.z + y.z) + b.z;
    float o3 = dv * (a.w + y.w) + b.w;
    if (RELU) {
        o0 = fmaxf(o0, 0.f); o1 = fmaxf(o1, 0.f);
        o2 = fmaxf(o2, 0.f); o3 = fmaxf(o3, 0.f);
    }
    float4 o = { o0, o1, o2, o3 };
    *(float4*)(Out + (size_t)n * EMB + j) = o;
}

extern "C" void kernel_launch(void* const* d_in, const int* in_sizes, int n_in,
                              void* d_out, int out_size, void* d_ws, size_t ws_size,
                              hipStream_t stream) {
    const int* ei = (const int*)d_in[0];
    const int E = in_sizes[0] / 2;
    const float* emb = (const float*)d_in[2];
    const int N = in_sizes[2] / EMB;
    const float* W1 = (const float*)d_in[3];
    const float* b1 = (const float*)d_in[4];
    const float* W2 = (const float*)d_in[5];
    const float* b2 = (const float*)d_in[6];
    float* out = (float*)d_out;

    const int* src = ei;
    const int* dstp = ei + E;

    // ws layout: dis[N] | A[N*128]  (~51.6 MB). d_out doubles as the scatter
    // accumulator for both layers to keep ws demand low.
    float* dis = (float*)d_ws;
    size_t off = ((size_t)N * 4 + 255) & ~(size_t)255;
    float* A = (float*)((char*)d_ws + off);
    const size_t big_bytes = (size_t)N * EMB * 4;

    // --- degree / normalization (shared by both layers) ---
    k_fill1<<<(N + 255) / 256, 256, 0, stream>>>(dis, N);
    k_deg_count<<<(E + 255) / 256, 256, 0, stream>>>(dstp, dis, E);
    k_rsqrt<<<(N + 255) / 256, 256, 0, stream>>>(dis, N);

    const long long st = (long long)E * 32;
    const long long ft = (long long)N * 32;
    const int gN = (N + 255) / 256;

    // --- layer 1: A = (emb@W1)*dis; out = scatter(A); A = relu(dis*(out+A)+b1) ---
    k_gemm_scale<<<gN, 256, 0, stream>>>(emb, W1, dis, A, N);
    hipMemsetAsync(out, 0, big_bytes, stream);
    k_scatter<<<(int)((st + 255) / 256), 256, 0, stream>>>(src, dstp, A, out, E);
    k_finalize<true><<<(int)((ft + 255) / 256), 256, 0, stream>>>(out, A, A, b1, dis, N);

    // --- layer 2: A = (A@W2)*dis (in-place); out = scatter(A); out = dis*(out+A)+b2 ---
    k_gemm_scale<<<gN, 256, 0, stream>>>(A, W2, dis, A, N);
    hipMemsetAsync(out, 0, big_bytes, stream);
    k_scatter<<<(int)((st + 255) / 256), 256, 0, stream>>>(src, dstp, A, out, E);
    k_finalize<false><<<(int)((ft + 255) / 256), 256, 0, stream>>>(out, A, out, b2, dis, N);
}

// Round 3
// 743.944 us; speedup vs baseline: 7.8200x; 7.8200x over previous
//
#include <hip/hip_runtime.h>

#define EMB 128

// ---------------- degree / normalization ----------------

__global__ void k_deg_count(const int* __restrict__ dst, int* deg, int E) {
    int e = blockIdx.x * blockDim.x + threadIdx.x;
    if (e < E) atomicAdd(&deg[dst[e]], 1);
}

__global__ void k_dis(const int* __restrict__ deg, float* __restrict__ dis, int N) {
    int i = blockIdx.x * blockDim.x + threadIdx.x;
    if (i < N) dis[i] = rsqrtf((float)deg[i] + 1.0f);   // +1 self-loop; always > 0
}

// ---------------- exclusive scan (3-kernel, 1024 elems/block) ----------------

__global__ __launch_bounds__(256) void k_scan1(const int* __restrict__ deg,
                                               int* __restrict__ R,
                                               int* __restrict__ S, int N) {
    __shared__ int ts[256];
    int base = blockIdx.x * 1024 + threadIdx.x * 4;
    int a0 = (base + 0 < N) ? deg[base + 0] : 0;
    int a1 = (base + 1 < N) ? deg[base + 1] : 0;
    int a2 = (base + 2 < N) ? deg[base + 2] : 0;
    int a3 = (base + 3 < N) ? deg[base + 3] : 0;
    int sum4 = a0 + a1 + a2 + a3;
    ts[threadIdx.x] = sum4;
    __syncthreads();
    for (int off = 1; off < 256; off <<= 1) {
        int v = (threadIdx.x >= off) ? ts[threadIdx.x - off] : 0;
        __syncthreads();
        ts[threadIdx.x] += v;
        __syncthreads();
    }
    int excl = ts[threadIdx.x] - sum4;   // exclusive prefix of this thread's chunk
    if (base + 0 < N) R[base + 0] = excl;
    if (base + 1 < N) R[base + 1] = excl + a0;
    if (base + 2 < N) R[base + 2] = excl + a0 + a1;
    if (base + 3 < N) R[base + 3] = excl + a0 + a1 + a2;
    if (threadIdx.x == 255) S[blockIdx.x] = ts[255];
}

__global__ void k_scan2(int* S, int nb) {   // tiny: one thread, exclusive scan of block sums
    if (blockIdx.x == 0 && threadIdx.x == 0) {
        int run = 0;
        for (int i = 0; i < nb; ++i) { int v = S[i]; S[i] = run; run += v; }
    }
}

__global__ __launch_bounds__(256) void k_scan3(int* __restrict__ R, int* __restrict__ C,
                                               const int* __restrict__ S, int N, int E) {
    int b = blockIdx.x;
    int add = S[b];
    int base = b * 1024 + threadIdx.x * 4;
#pragma unroll
    for (int t = 0; t < 4; ++t) {
        int i = base + t;
        if (i < N) { int v = R[i] + add; R[i] = v; C[i] = v; }
    }
    if (b == 0 && threadIdx.x == 0) R[N] = E;
}

// ---------------- CSR bucket fill ----------------

__global__ void k_fill_adj(const int* __restrict__ src, const int* __restrict__ dst,
                           int* __restrict__ C, int* __restrict__ adj, int E) {
    int e = blockIdx.x * blockDim.x + threadIdx.x;
    if (e < E) {
        int pos = atomicAdd(&C[dst[e]], 1);
        adj[pos] = src[e];
    }
}

// ---------------- Y[n] = (X[n] @ W) * dis[n]; W staged in LDS ----------------
// No __restrict__ on X/Y: the layer-2 call runs in-place (safe: each thread
// reads only its own row fully into registers before writing it).
__global__ __launch_bounds__(256) void k_gemm_scale(
    const float* X, const float* __restrict__ W,
    const float* __restrict__ dis, float* Y, int N)
{
    __shared__ float Ws[EMB * EMB];   // 64 KB
    for (int i = threadIdx.x; i < EMB * EMB; i += 256) Ws[i] = W[i];
    __syncthreads();
    int n = blockIdx.x * 256 + threadIdx.x;
    if (n >= N) return;

    float acc[EMB];
#pragma unroll
    for (int j = 0; j < EMB; ++j) acc[j] = 0.0f;

#pragma unroll 1
    for (int k0 = 0; k0 < EMB; k0 += 8) {
        const float4* xp = (const float4*)(X + (size_t)n * EMB + k0);
        float4 u0 = xp[0], u1 = xp[1];
        float a[8] = { u0.x, u0.y, u0.z, u0.w, u1.x, u1.y, u1.z, u1.w };
#pragma unroll
        for (int kk = 0; kk < 8; ++kk) {
            const float* wr = &Ws[(k0 + kk) * EMB];
#pragma unroll
            for (int j = 0; j < EMB; j += 4) {
                float4 w = *(const float4*)(wr + j);
                acc[j+0] += a[kk] * w.x;
                acc[j+1] += a[kk] * w.y;
                acc[j+2] += a[kk] * w.z;
                acc[j+3] += a[kk] * w.w;
            }
        }
    }

    float dv = dis[n];
    float* yr = Y + (size_t)n * EMB;
#pragma unroll
    for (int j = 0; j < EMB; j += 4) {
        float4 o = { acc[j]*dv, acc[j+1]*dv, acc[j+2]*dv, acc[j+3]*dv };
        *(float4*)(yr + j) = o;
    }
}

// ---------------- fused gather + normalize + bias (+relu) ----------------
// 32-lane group per node; lane covers 4 consecutive cols (float4).
// Out[n] = act(dis[n] * (Y[n] + sum_{e in CSR row n} Y[adj[e]]) + b)
template <bool RELU>
__global__ __launch_bounds__(256) void k_gather_finalize(
    const int* __restrict__ R, const int* __restrict__ adj,
    const float* __restrict__ Y, const float* __restrict__ dis,
    const float* __restrict__ bias, float* __restrict__ Out, int N)
{
    int t = blockIdx.x * 256 + threadIdx.x;
    int n = t >> 5;
    if (n >= N) return;
    int j = (t & 31) * 4;

    int rs = R[n], re = R[n + 1];

    // self-loop term
    const float4 sv = *(const float4*)(Y + (size_t)n * EMB + j);
    float a0 = sv.x, a1 = sv.y, a2 = sv.z, a3 = sv.w;

    int e = rs;
    for (; e + 1 < re; e += 2) {
        int s0 = adj[e], s1 = adj[e + 1];
        float4 v0 = *(const float4*)(Y + (size_t)s0 * EMB + j);
        float4 v1 = *(const float4*)(Y + (size_t)s1 * EMB + j);
        a0 += v0.x; a1 += v0.y; a2 += v0.z; a3 += v0.w;
        a0 += v1.x; a1 += v1.y; a2 += v1.z; a3 += v1.w;
    }
    if (e < re) {
        int s0 = adj[e];
        float4 v0 = *(const float4*)(Y + (size_t)s0 * EMB + j);
        a0 += v0.x; a1 += v0.y; a2 += v0.z; a3 += v0.w;
    }

    float dv = dis[n];
    float4 b = *(const float4*)(bias + j);
    float o0 = dv * a0 + b.x;
    float o1 = dv * a1 + b.y;
    float o2 = dv * a2 + b.z;
    float o3 = dv * a3 + b.w;
    if (RELU) {
        o0 = fmaxf(o0, 0.f); o1 = fmaxf(o1, 0.f);
        o2 = fmaxf(o2, 0.f); o3 = fmaxf(o3, 0.f);
    }
    float4 o = { o0, o1, o2, o3 };
    *(float4*)(Out + (size_t)n * EMB + j) = o;
}

extern "C" void kernel_launch(void* const* d_in, const int* in_sizes, int n_in,
                              void* d_out, int out_size, void* d_ws, size_t ws_size,
                              hipStream_t stream) {
    const int* ei = (const int*)d_in[0];
    const int E = in_sizes[0] / 2;
    const float* emb = (const float*)d_in[2];
    const int N = in_sizes[2] / EMB;
    const float* W1 = (const float*)d_in[3];
    const float* b1 = (const float*)d_in[4];
    const float* W2 = (const float*)d_in[5];
    const float* b2 = (const float*)d_in[6];
    float* out = (float*)d_out;

    const int* src = ei;
    const int* dstp = ei + E;

    // ws layout (small arrays first, big H last):
    //   dis[N] f32 | deg[N] i32 | R[N+1] i32 | C[N] i32 | S[nsb] i32 | adj[E] i32 | H[N*128] f32
    char* w = (char*)d_ws;
    auto take = [&](size_t bytes) { char* p = w; w += (bytes + 511) & ~(size_t)511; return p; };
    const int NB = (N + 1023) / 1024;                 // scan blocks
    float* dis = (float*)take((size_t)N * 4);
    int*   deg = (int*)  take((size_t)N * 4);
    int*   R   = (int*)  take((size_t)(N + 1) * 4);
    int*   C   = (int*)  take((size_t)N * 4);
    int*   S   = (int*)  take((size_t)NB * 4);
    int*   adj = (int*)  take((size_t)E * 4);
    float* H   = (float*)take((size_t)N * EMB * 4);

    const int gE = (E + 255) / 256;
    const int gN = (N + 255) / 256;
    const int gG = (N * 32 + 255) / 256;

    // --- CSR build (shared by both layers) ---
    hipMemsetAsync(deg, 0, (size_t)N * 4, stream);
    k_deg_count<<<gE, 256, 0, stream>>>(dstp, deg, E);
    k_dis<<<gN, 256, 0, stream>>>(deg, dis, N);
    k_scan1<<<NB, 256, 0, stream>>>(deg, R, S, N);
    k_scan2<<<1, 64, 0, stream>>>(S, NB);
    k_scan3<<<NB, 256, 0, stream>>>(R, C, S, N, E);
    k_fill_adj<<<gE, 256, 0, stream>>>(src, dstp, C, adj, E);

    // --- layer 1: out(scratch) = (emb@W1)*dis; H = relu(dis*(gather+self)+b1) ---
    k_gemm_scale<<<gN, 256, 0, stream>>>(emb, W1, dis, out, N);
    k_gather_finalize<true><<<gG, 256, 0, stream>>>(R, adj, out, dis, b1, H, N);

    // --- layer 2: H = (H@W2)*dis (in-place); out = dis*(gather+self)+b2 ---
    k_gemm_scale<<<gN, 256, 0, stream>>>(H, W2, dis, H, N);
    k_gather_finalize<false><<<gG, 256, 0, stream>>>(R, adj, H, dis, b2, out, N);
}

// Round 4
// 682.823 us; speedup vs baseline: 8.5200x; 1.0895x over previous
//
#include <hip/hip_runtime.h>

#define EMB 128

// ---------------- degree / normalization ----------------

__global__ void k_deg_count(const int* __restrict__ dst, int* deg, int E) {
    int e = blockIdx.x * blockDim.x + threadIdx.x;
    if (e < E) atomicAdd(&deg[dst[e]], 1);
}

__global__ void k_dis(const int* __restrict__ deg, float* __restrict__ dis, int N) {
    int i = blockIdx.x * blockDim.x + threadIdx.x;
    if (i < N) dis[i] = rsqrtf((float)deg[i] + 1.0f);   // +1 self-loop; always > 0
}

// ---------------- exclusive scan (3-kernel, 1024 elems/block) ----------------

__global__ __launch_bounds__(256) void k_scan1(const int* __restrict__ deg,
                                               int* __restrict__ R,
                                               int* __restrict__ S, int N) {
    __shared__ int ts[256];
    int base = blockIdx.x * 1024 + threadIdx.x * 4;
    int a0 = (base + 0 < N) ? deg[base + 0] : 0;
    int a1 = (base + 1 < N) ? deg[base + 1] : 0;
    int a2 = (base + 2 < N) ? deg[base + 2] : 0;
    int a3 = (base + 3 < N) ? deg[base + 3] : 0;
    int sum4 = a0 + a1 + a2 + a3;
    ts[threadIdx.x] = sum4;
    __syncthreads();
    for (int off = 1; off < 256; off <<= 1) {
        int v = (threadIdx.x >= off) ? ts[threadIdx.x - off] : 0;
        __syncthreads();
        ts[threadIdx.x] += v;
        __syncthreads();
    }
    int excl = ts[threadIdx.x] - sum4;   // exclusive prefix of this thread's chunk
    if (base + 0 < N) R[base + 0] = excl;
    if (base + 1 < N) R[base + 1] = excl + a0;
    if (base + 2 < N) R[base + 2] = excl + a0 + a1;
    if (base + 3 < N) R[base + 3] = excl + a0 + a1 + a2;
    if (threadIdx.x == 255) S[blockIdx.x] = ts[255];
}

__global__ void k_scan2(int* S, int nb) {   // tiny: one thread, exclusive scan of block sums
    if (blockIdx.x == 0 && threadIdx.x == 0) {
        int run = 0;
        for (int i = 0; i < nb; ++i) { int v = S[i]; S[i] = run; run += v; }
    }
}

__global__ __launch_bounds__(256) void k_scan3(int* __restrict__ R, int* __restrict__ C,
                                               const int* __restrict__ S, int N, int E) {
    int b = blockIdx.x;
    int add = S[b];
    int base = b * 1024 + threadIdx.x * 4;
#pragma unroll
    for (int t = 0; t < 4; ++t) {
        int i = base + t;
        if (i < N) { int v = R[i] + add; R[i] = v; C[i] = v; }
    }
    if (b == 0 && threadIdx.x == 0) R[N] = E;
}

// ---------------- CSR bucket fill ----------------

__global__ void k_fill_adj(const int* __restrict__ src, const int* __restrict__ dst,
                           int* __restrict__ C, int* __restrict__ adj, int E) {
    int e = blockIdx.x * blockDim.x + threadIdx.x;
    if (e < E) {
        int pos = atomicAdd(&C[dst[e]], 1);
        adj[pos] = src[e];
    }
}

// ---------------- Y[n] = (X[n] @ W) * dis[n]; W staged in LDS ----------------
// Thread tiling: 4 nodes x 32 cols per thread (cg = tid&3 owns interleaved
// cols {16j + 4cg .. +3}); block covers 256 nodes, all 128 cols.
//  - W-read : FMA ratio = 8 ds_read_b128 : 128 FMA per k-step (vs 32:128 in the
//    1-node version, which was ds_read-throughput bound at ~12cyc/b128).
//  - interleaved cg mapping: the 4 distinct LDS addresses per read sit on
//    disjoint bank groups (cg*4 mod 32 = 0/4/8/12) -> conflict-free; and the
//    4 cg lanes store contiguous 64B -> coalesced writes.
//  - In-place (X==Y, layer 2) is safe: all row reads are by threads of the
//    owning block, and __syncthreads() separates the k-loop from the stores.
__global__ __launch_bounds__(256, 2) void k_gemm_scale(
    const float* X, const float* __restrict__ W,
    const float* __restrict__ dis, float* Y, int N)
{
    __shared__ float Ws[EMB * EMB];   // 64 KB
    for (int i = threadIdx.x * 4; i < EMB * EMB; i += 256 * 4)
        *(float4*)&Ws[i] = *(const float4*)&W[i];
    __syncthreads();

    const int cg = threadIdx.x & 3;
    const int ns = threadIdx.x >> 2;
    const int base = blockIdx.x * 256;

    int n[4], nc[4];
#pragma unroll
    for (int i = 0; i < 4; ++i) {
        n[i] = base + ns + 64 * i;
        nc[i] = n[i] < N ? n[i] : (N - 1);   // clamp stays inside this block's rows
    }

    float4 acc[4][8];
#pragma unroll
    for (int i = 0; i < 4; ++i)
#pragma unroll
        for (int j = 0; j < 8; ++j) acc[i][j] = make_float4(0.f, 0.f, 0.f, 0.f);

#pragma unroll 1
    for (int k0 = 0; k0 < EMB; k0 += 8) {
        float a[4][8];
#pragma unroll
        for (int i = 0; i < 4; ++i) {
            const float4* xp = (const float4*)(X + (size_t)nc[i] * EMB + k0);
            float4 u0 = xp[0], u1 = xp[1];
            a[i][0]=u0.x; a[i][1]=u0.y; a[i][2]=u0.z; a[i][3]=u0.w;
            a[i][4]=u1.x; a[i][5]=u1.y; a[i][6]=u1.z; a[i][7]=u1.w;
        }
#pragma unroll
        for (int kk = 0; kk < 8; ++kk) {
            const float* wr = &Ws[(k0 + kk) * EMB + cg * 4];
            float4 w[8];
#pragma unroll
            for (int j = 0; j < 8; ++j) w[j] = *(const float4*)(wr + j * 16);
#pragma unroll
            for (int i = 0; i < 4; ++i) {
                float av = a[i][kk];
#pragma unroll
                for (int j = 0; j < 8; ++j) {
                    acc[i][j].x += av * w[j].x;
                    acc[i][j].y += av * w[j].y;
                    acc[i][j].z += av * w[j].z;
                    acc[i][j].w += av * w[j].w;
                }
            }
        }
    }

    __syncthreads();   // in-place safety: all X reads complete before any Y write

#pragma unroll
    for (int i = 0; i < 4; ++i) {
        if (n[i] < N) {
            float dv = dis[n[i]];
            float* yr = Y + (size_t)n[i] * EMB + cg * 4;
#pragma unroll
            for (int j = 0; j < 8; ++j) {
                float4 o = { acc[i][j].x * dv, acc[i][j].y * dv,
                             acc[i][j].z * dv, acc[i][j].w * dv };
                *(float4*)(yr + j * 16) = o;
            }
        }
    }
}

// ---------------- fused gather + normalize + bias (+relu) ----------------
// 32-lane group per node; lane covers 4 consecutive cols (float4).
// Out[n] = act(dis[n] * (Y[n] + sum_{e in CSR row n} Y[adj[e]]) + b)
template <bool RELU>
__global__ __launch_bounds__(256) void k_gather_finalize(
    const int* __restrict__ R, const int* __restrict__ adj,
    const float* __restrict__ Y, const float* __restrict__ dis,
    const float* __restrict__ bias, float* __restrict__ Out, int N)
{
    int t = blockIdx.x * 256 + threadIdx.x;
    int n = t >> 5;
    if (n >= N) return;
    int j = (t & 31) * 4;

    int rs = R[n], re = R[n + 1];

    // self-loop term
    const float4 sv = *(const float4*)(Y + (size_t)n * EMB + j);
    float a0 = sv.x, a1 = sv.y, a2 = sv.z, a3 = sv.w;

    int e = rs;
    for (; e + 3 < re; e += 4) {
        int s0 = adj[e], s1 = adj[e + 1], s2 = adj[e + 2], s3 = adj[e + 3];
        float4 v0 = *(const float4*)(Y + (size_t)s0 * EMB + j);
        float4 v1 = *(const float4*)(Y + (size_t)s1 * EMB + j);
        float4 v2 = *(const float4*)(Y + (size_t)s2 * EMB + j);
        float4 v3 = *(const float4*)(Y + (size_t)s3 * EMB + j);
        a0 += v0.x; a1 += v0.y; a2 += v0.z; a3 += v0.w;
        a0 += v1.x; a1 += v1.y; a2 += v1.z; a3 += v1.w;
        a0 += v2.x; a1 += v2.y; a2 += v2.z; a3 += v2.w;
        a0 += v3.x; a1 += v3.y; a2 += v3.z; a3 += v3.w;
    }
    for (; e < re; ++e) {
        int s0 = adj[e];
        float4 v0 = *(const float4*)(Y + (size_t)s0 * EMB + j);
        a0 += v0.x; a1 += v0.y; a2 += v0.z; a3 += v0.w;
    }

    float dv = dis[n];
    float4 b = *(const float4*)(bias + j);
    float o0 = dv * a0 + b.x;
    float o1 = dv * a1 + b.y;
    float o2 = dv * a2 + b.z;
    float o3 = dv * a3 + b.w;
    if (RELU) {
        o0 = fmaxf(o0, 0.f); o1 = fmaxf(o1, 0.f);
        o2 = fmaxf(o2, 0.f); o3 = fmaxf(o3, 0.f);
    }
    float4 o = { o0, o1, o2, o3 };
    *(float4*)(Out + (size_t)n * EMB + j) = o;
}

extern "C" void kernel_launch(void* const* d_in, const int* in_sizes, int n_in,
                              void* d_out, int out_size, void* d_ws, size_t ws_size,
                              hipStream_t stream) {
    const int* ei = (const int*)d_in[0];
    const int E = in_sizes[0] / 2;
    const float* emb = (const float*)d_in[2];
    const int N = in_sizes[2] / EMB;
    const float* W1 = (const float*)d_in[3];
    const float* b1 = (const float*)d_in[4];
    const float* W2 = (const float*)d_in[5];
    const float* b2 = (const float*)d_in[6];
    float* out = (float*)d_out;

    const int* src = ei;
    const int* dstp = ei + E;

    // ws layout (small arrays first, big H last):
    //   dis[N] f32 | deg[N] i32 | R[N+1] i32 | C[N] i32 | S[nsb] i32 | adj[E] i32 | H[N*128] f32
    char* w = (char*)d_ws;
    auto take = [&](size_t bytes) { char* p = w; w += (bytes + 511) & ~(size_t)511; return p; };
    const int NB = (N + 1023) / 1024;                 // scan blocks
    float* dis = (float*)take((size_t)N * 4);
    int*   deg = (int*)  take((size_t)N * 4);
    int*   R   = (int*)  take((size_t)(N + 1) * 4);
    int*   C   = (int*)  take((size_t)N * 4);
    int*   S   = (int*)  take((size_t)NB * 4);
    int*   adj = (int*)  take((size_t)E * 4);
    float* H   = (float*)take((size_t)N * EMB * 4);

    const int gE = (E + 255) / 256;
    const int gN = (N + 255) / 256;
    const int gG = (N * 32 + 255) / 256;

    // --- CSR build (shared by both layers) ---
    hipMemsetAsync(deg, 0, (size_t)N * 4, stream);
    k_deg_count<<<gE, 256, 0, stream>>>(dstp, deg, E);
    k_dis<<<gN, 256, 0, stream>>>(deg, dis, N);
    k_scan1<<<NB, 256, 0, stream>>>(deg, R, S, N);
    k_scan2<<<1, 64, 0, stream>>>(S, NB);
    k_scan3<<<NB, 256, 0, stream>>>(R, C, S, N, E);
    k_fill_adj<<<gE, 256, 0, stream>>>(src, dstp, C, adj, E);

    // --- layer 1: out(scratch) = (emb@W1)*dis; H = relu(dis*(gather+self)+b1) ---
    k_gemm_scale<<<gN, 256, 0, stream>>>(emb, W1, dis, out, N);
    k_gather_finalize<true><<<gG, 256, 0, stream>>>(R, adj, out, dis, b1, H, N);

    // --- layer 2: H = (H@W2)*dis (in-place); out = dis*(gather+self)+b2 ---
    k_gemm_scale<<<gN, 256, 0, stream>>>(H, W2, dis, H, N);
    k_gather_finalize<false><<<gG, 256, 0, stream>>>(R, adj, H, dis, b2, out, N);
}

// Round 5
// 563.838 us; speedup vs baseline: 10.3180x; 1.2110x over previous
//
#include <hip/hip_runtime.h>

#define EMB 128
#define NBUC 1024          // coarse buckets: dst >> 7 (128 nodes per bucket)
#define NPART 256          // partition blocks for P1/P2

// ============ CSR build: atomic-light two-level counting sort ============

// P1: per-block LDS histogram over coarse buckets; no global atomics.
__global__ __launch_bounds__(256) void p1_hist(const int* __restrict__ dst,
                                               int* __restrict__ BH, int E, int chunk) {
    __shared__ int h[NBUC];
#pragma unroll
    for (int i = threadIdx.x; i < NBUC; i += 256) h[i] = 0;
    __syncthreads();
    int s = blockIdx.x * chunk;
    int e = min(E, s + chunk);
    for (int i = s + threadIdx.x; i < e; i += 256)
        atomicAdd(&h[dst[i] >> 7], 1);
    __syncthreads();
    for (int i = threadIdx.x; i < NBUC; i += 256)
        BH[blockIdx.x * NBUC + i] = h[i];
}

// tot[b] = sum over blocks of BH[blk][b]
__global__ __launch_bounds__(256) void p_tot(const int* __restrict__ BH,
                                             int* __restrict__ tot) {
    int b = blockIdx.x * 256 + threadIdx.x;   // grid 4*256 = 1024
    int s = 0;
    for (int blk = 0; blk < NPART; ++blk) s += BH[blk * NBUC + b];
    tot[b] = s;
}

// base = exclusive scan of tot (single block, 1024 threads); base[NBUC] = E.
__global__ __launch_bounds__(1024) void p_scan(const int* __restrict__ tot,
                                               int* __restrict__ base, int E) {
    __shared__ int a[NBUC];
    int t = threadIdx.x;
    int v0 = tot[t];
    a[t] = v0;
    __syncthreads();
    for (int off = 1; off < NBUC; off <<= 1) {
        int v = (t >= off) ? a[t - off] : 0;
        __syncthreads();
        a[t] += v;
        __syncthreads();
    }
    base[t] = a[t] - v0;          // exclusive
    if (t == NBUC - 1) base[NBUC] = E;
}

// offs (in-place over BH): BH[blk][b] = base[b] + prefix over earlier blocks.
__global__ __launch_bounds__(256) void p_offs(int* __restrict__ BH,
                                              const int* __restrict__ base) {
    int b = blockIdx.x * 256 + threadIdx.x;   // grid 4*256 = 1024
    int run = base[b];
    for (int blk = 0; blk < NPART; ++blk) {
        int* p = &BH[blk * NBUC + b];
        int v = *p;
        *p = run;
        run += v;
    }
}

// P2: scatter packed edges into bucket-contiguous part[]; LDS counters hold
// global positions -> writes form 1024 quasi-sequential streams per block.
__global__ __launch_bounds__(256) void p2_scatter(const int* __restrict__ src,
                                                  const int* __restrict__ dst,
                                                  const int* __restrict__ BH,
                                                  int* __restrict__ part,
                                                  int E, int chunk) {
    __shared__ int cnt[NBUC];
    for (int i = threadIdx.x; i < NBUC; i += 256)
        cnt[i] = BH[blockIdx.x * NBUC + i];
    __syncthreads();
    int s = blockIdx.x * chunk;
    int e = min(E, s + chunk);
    for (int i = s + threadIdx.x; i < e; i += 256) {
        int d = dst[i];
        int pos = atomicAdd(&cnt[d >> 7], 1);
        part[pos] = src[i] | ((d & 127) << 17);   // src < 2^17, local node in [0,128)
    }
}

// P3: per-bucket fine CSR in LDS; emits R, dis (degree fused), adj.
__global__ __launch_bounds__(256) void p3_csr(const int* __restrict__ part,
                                              const int* __restrict__ base,
                                              int* __restrict__ R, int* __restrict__ adj,
                                              float* __restrict__ dis, int N, int E) {
    __shared__ int hist[128];
    __shared__ int sc[128];
    __shared__ int cnt[128];
    int b = blockIdx.x;
    int n0 = b * 128;
    int nn = min(128, N - n0);
    int s = base[b], e = base[b + 1];
    int t = threadIdx.x;

    if (t < 128) hist[t] = 0;
    __syncthreads();
    for (int i = s + t; i < e; i += 256)
        atomicAdd(&hist[part[i] >> 17], 1);
    __syncthreads();

    // exclusive scan of hist[0..127] (all 256 threads hit the barriers)
    if (t < 128) sc[t] = hist[t];
    __syncthreads();
    for (int off = 1; off < 128; off <<= 1) {
        int v = 0;
        if (t < 128 && t >= off) v = sc[t - off];
        __syncthreads();
        if (t < 128) sc[t] += v;
        __syncthreads();
    }
    if (t < 128) {
        int excl = sc[t] - hist[t];
        cnt[t] = excl;
        if (t < nn) {
            R[n0 + t] = s + excl;
            dis[n0 + t] = rsqrtf((float)hist[t] + 1.0f);   // +1 self-loop
        }
    }
    if (b == 0 && t == 0) R[N] = E;
    __syncthreads();

    for (int i = s + t; i < e; i += 256) {
        int p = part[i];
        int pos = atomicAdd(&cnt[p >> 17], 1);
        adj[s + pos] = p & 0x1FFFF;
    }
}

// ---------------- Y[n] = (X[n] @ W) * dis[n]; W staged in LDS ----------------
// 4 nodes x 32 interleaved cols per thread; see R3->R4 notes. In-place safe
// (layer 2): __syncthreads() separates all X reads from Y writes; clamp keeps
// OOB lanes inside this block's row range.
__global__ __launch_bounds__(256, 2) void k_gemm_scale(
    const float* X, const float* __restrict__ W,
    const float* __restrict__ dis, float* Y, int N)
{
    __shared__ float Ws[EMB * EMB];   // 64 KB
    for (int i = threadIdx.x * 4; i < EMB * EMB; i += 256 * 4)
        *(float4*)&Ws[i] = *(const float4*)&W[i];
    __syncthreads();

    const int cg = threadIdx.x & 3;
    const int ns = threadIdx.x >> 2;
    const int base = blockIdx.x * 256;

    int n[4], nc[4];
#pragma unroll
    for (int i = 0; i < 4; ++i) {
        n[i] = base + ns + 64 * i;
        nc[i] = n[i] < N ? n[i] : (N - 1);
    }

    float4 acc[4][8];
#pragma unroll
    for (int i = 0; i < 4; ++i)
#pragma unroll
        for (int j = 0; j < 8; ++j) acc[i][j] = make_float4(0.f, 0.f, 0.f, 0.f);

#pragma unroll 1
    for (int k0 = 0; k0 < EMB; k0 += 8) {
        float a[4][8];
#pragma unroll
        for (int i = 0; i < 4; ++i) {
            const float4* xp = (const float4*)(X + (size_t)nc[i] * EMB + k0);
            float4 u0 = xp[0], u1 = xp[1];
            a[i][0]=u0.x; a[i][1]=u0.y; a[i][2]=u0.z; a[i][3]=u0.w;
            a[i][4]=u1.x; a[i][5]=u1.y; a[i][6]=u1.z; a[i][7]=u1.w;
        }
#pragma unroll
        for (int kk = 0; kk < 8; ++kk) {
            const float* wr = &Ws[(k0 + kk) * EMB + cg * 4];
            float4 w[8];
#pragma unroll
            for (int j = 0; j < 8; ++j) w[j] = *(const float4*)(wr + j * 16);
#pragma unroll
            for (int i = 0; i < 4; ++i) {
                float av = a[i][kk];
#pragma unroll
                for (int j = 0; j < 8; ++j) {
                    acc[i][j].x += av * w[j].x;
                    acc[i][j].y += av * w[j].y;
                    acc[i][j].z += av * w[j].z;
                    acc[i][j].w += av * w[j].w;
                }
            }
        }
    }

    __syncthreads();   // in-place safety: all X reads complete before any Y write

#pragma unroll
    for (int i = 0; i < 4; ++i) {
        if (n[i] < N) {
            float dv = dis[n[i]];
            float* yr = Y + (size_t)n[i] * EMB + cg * 4;
#pragma unroll
            for (int j = 0; j < 8; ++j) {
                float4 o = { acc[i][j].x * dv, acc[i][j].y * dv,
                             acc[i][j].z * dv, acc[i][j].w * dv };
                *(float4*)(yr + j * 16) = o;
            }
        }
    }
}

// ---------------- fused gather + normalize + bias (+relu) ----------------
template <bool RELU>
__global__ __launch_bounds__(256) void k_gather_finalize(
    const int* __restrict__ R, const int* __restrict__ adj,
    const float* __restrict__ Y, const float* __restrict__ dis,
    const float* __restrict__ bias, float* __restrict__ Out, int N)
{
    int t = blockIdx.x * 256 + threadIdx.x;
    int n = t >> 5;
    if (n >= N) return;
    int j = (t & 31) * 4;

    int rs = R[n], re = R[n + 1];

    const float4 sv = *(const float4*)(Y + (size_t)n * EMB + j);
    float a0 = sv.x, a1 = sv.y, a2 = sv.z, a3 = sv.w;

    int e = rs;
    for (; e + 3 < re; e += 4) {
        int s0 = adj[e], s1 = adj[e + 1], s2 = adj[e + 2], s3 = adj[e + 3];
        float4 v0 = *(const float4*)(Y + (size_t)s0 * EMB + j);
        float4 v1 = *(const float4*)(Y + (size_t)s1 * EMB + j);
        float4 v2 = *(const float4*)(Y + (size_t)s2 * EMB + j);
        float4 v3 = *(const float4*)(Y + (size_t)s3 * EMB + j);
        a0 += v0.x; a1 += v0.y; a2 += v0.z; a3 += v0.w;
        a0 += v1.x; a1 += v1.y; a2 += v1.z; a3 += v1.w;
        a0 += v2.x; a1 += v2.y; a2 += v2.z; a3 += v2.w;
        a0 += v3.x; a1 += v3.y; a2 += v3.z; a3 += v3.w;
    }
    for (; e < re; ++e) {
        int s0 = adj[e];
        float4 v0 = *(const float4*)(Y + (size_t)s0 * EMB + j);
        a0 += v0.x; a1 += v0.y; a2 += v0.z; a3 += v0.w;
    }

    float dv = dis[n];
    float4 b = *(const float4*)(bias + j);
    float o0 = dv * a0 + b.x;
    float o1 = dv * a1 + b.y;
    float o2 = dv * a2 + b.z;
    float o3 = dv * a3 + b.w;
    if (RELU) {
        o0 = fmaxf(o0, 0.f); o1 = fmaxf(o1, 0.f);
        o2 = fmaxf(o2, 0.f); o3 = fmaxf(o3, 0.f);
    }
    float4 o = { o0, o1, o2, o3 };
    *(float4*)(Out + (size_t)n * EMB + j) = o;
}

extern "C" void kernel_launch(void* const* d_in, const int* in_sizes, int n_in,
                              void* d_out, int out_size, void* d_ws, size_t ws_size,
                              hipStream_t stream) {
    const int* ei = (const int*)d_in[0];
    const int E = in_sizes[0] / 2;
    const float* emb = (const float*)d_in[2];
    const int N = in_sizes[2] / EMB;
    const float* W1 = (const float*)d_in[3];
    const float* b1 = (const float*)d_in[4];
    const float* W2 = (const float*)d_in[5];
    const float* b2 = (const float*)d_in[6];
    float* out = (float*)d_out;

    const int* src = ei;
    const int* dstp = ei + E;

    // ws layout: dis[N] | R[N+1] | base[NBUC+1] | tot[NBUC] | adj[E] | H[N*128]
    // part[E] and BH[NPART*NBUC] overlay H's storage: both are dead before the
    // first write to H (gather-L1).  Total ~58.5 MB (<= 59.3 MB proven in R4).
    char* w = (char*)d_ws;
    auto take = [&](size_t bytes) { char* p = w; w += (bytes + 511) & ~(size_t)511; return p; };
    float* dis  = (float*)take((size_t)N * 4);
    int*   R    = (int*)  take((size_t)(N + 1) * 4);
    int*   base = (int*)  take((size_t)(NBUC + 1) * 4);
    int*   tot  = (int*)  take((size_t)NBUC * 4);
    int*   adj  = (int*)  take((size_t)E * 4);
    float* H    = (float*)take((size_t)N * EMB * 4);
    int*   part = (int*)H;                                   // overlay (dead before H)
    int*   BH   = (int*)((char*)H + (((size_t)E * 4 + 511) & ~(size_t)511));

    const int NB = (N + 127) / 128;          // fine buckets actually populated
    const int chunk = (E + NPART - 1) / NPART;
    const int gN = (N + 255) / 256;
    const int gG = (N * 32 + 255) / 256;

    // --- CSR + dis build (shared by both layers) ---
    p1_hist   <<<NPART, 256, 0, stream>>>(dstp, BH, E, chunk);
    p_tot     <<<NBUC / 256, 256, 0, stream>>>(BH, tot);
    p_scan    <<<1, NBUC, 0, stream>>>(tot, base, E);
    p_offs    <<<NBUC / 256, 256, 0, stream>>>(BH, base);
    p2_scatter<<<NPART, 256, 0, stream>>>(src, dstp, BH, part, E, chunk);
    p3_csr    <<<NB, 256, 0, stream>>>(part, base, R, adj, dis, N, E);

    // --- layer 1: out(scratch) = (emb@W1)*dis; H = relu(dis*(gather+self)+b1) ---
    k_gemm_scale<<<gN, 256, 0, stream>>>(emb, W1, dis, out, N);
    k_gather_finalize<true><<<gG, 256, 0, stream>>>(R, adj, out, dis, b1, H, N);

    // --- layer 2: H = (H@W2)*dis (in-place); out = dis*(gather+self)+b2 ---
    k_gemm_scale<<<gN, 256, 0, stream>>>(H, W2, dis, H, N);
    k_gather_finalize<false><<<gG, 256, 0, stream>>>(R, adj, H, dis, b2, out, N);
}

// Round 6
// 443.927 us; speedup vs baseline: 13.1050x; 1.2701x over previous
//
#include <hip/hip_runtime.h>

#define EMB 128
#define NBUC 1024          // coarse buckets: dst >> 7 (128 nodes per bucket)
#define NPART 256          // partition blocks for P1/P2

// ---------------- bf16 helpers ----------------
__device__ __forceinline__ unsigned short f2bf(float f) {
    union { float f; unsigned int i; } v; v.f = f;
    unsigned int x = v.i;
    x += 0x7fffu + ((x >> 16) & 1u);   // round-to-nearest-even
    return (unsigned short)(x >> 16);
}
// accumulate 4 bf16 (packed in uint2, little-endian e0..e3) into 4 f32
__device__ __forceinline__ void acc_bf4(uint2 v, float& a0, float& a1, float& a2, float& a3) {
    union { unsigned int i; float f; } t;
    t.i = v.x << 16;          a0 += t.f;
    t.i = v.x & 0xffff0000u;  a1 += t.f;
    t.i = v.y << 16;          a2 += t.f;
    t.i = v.y & 0xffff0000u;  a3 += t.f;
}
__device__ __forceinline__ float bfu2f(unsigned int lo16) {
    union { unsigned int i; float f; } t; t.i = lo16 << 16; return t.f;
}

// ============ CSR build: atomic-light two-level counting sort ============

__global__ __launch_bounds__(256) void p1_hist(const int* __restrict__ dst,
                                               int* __restrict__ BH, int E, int chunk) {
    __shared__ int h[NBUC];
    for (int i = threadIdx.x; i < NBUC; i += 256) h[i] = 0;
    __syncthreads();
    int s = blockIdx.x * chunk;
    int e = min(E, s + chunk);
    for (int i = s + threadIdx.x; i < e; i += 256)
        atomicAdd(&h[dst[i] >> 7], 1);
    __syncthreads();
    for (int i = threadIdx.x; i < NBUC; i += 256)
        BH[blockIdx.x * NBUC + i] = h[i];
}

__global__ __launch_bounds__(256) void p_tot(const int* __restrict__ BH,
                                             int* __restrict__ tot) {
    int b = blockIdx.x * 256 + threadIdx.x;
    int s = 0;
    for (int blk = 0; blk < NPART; ++blk) s += BH[blk * NBUC + b];
    tot[b] = s;
}

__global__ __launch_bounds__(1024) void p_scan(const int* __restrict__ tot,
                                               int* __restrict__ base, int E) {
    __shared__ int a[NBUC];
    int t = threadIdx.x;
    int v0 = tot[t];
    a[t] = v0;
    __syncthreads();
    for (int off = 1; off < NBUC; off <<= 1) {
        int v = (t >= off) ? a[t - off] : 0;
        __syncthreads();
        a[t] += v;
        __syncthreads();
    }
    base[t] = a[t] - v0;
    if (t == NBUC - 1) base[NBUC] = E;
}

__global__ __launch_bounds__(256) void p_offs(int* __restrict__ BH,
                                              const int* __restrict__ base) {
    int b = blockIdx.x * 256 + threadIdx.x;
    int run = base[b];
    for (int blk = 0; blk < NPART; ++blk) {
        int* p = &BH[blk * NBUC + b];
        int v = *p;
        *p = run;
        run += v;
    }
}

__global__ __launch_bounds__(256) void p2_scatter(const int* __restrict__ src,
                                                  const int* __restrict__ dst,
                                                  const int* __restrict__ BH,
                                                  int* __restrict__ part,
                                                  int E, int chunk) {
    __shared__ int cnt[NBUC];
    for (int i = threadIdx.x; i < NBUC; i += 256)
        cnt[i] = BH[blockIdx.x * NBUC + i];
    __syncthreads();
    int s = blockIdx.x * chunk;
    int e = min(E, s + chunk);
    for (int i = s + threadIdx.x; i < e; i += 256) {
        int d = dst[i];
        int pos = atomicAdd(&cnt[d >> 7], 1);
        part[pos] = src[i] | ((d & 127) << 17);   // src < 2^17, local node in [0,128)
    }
}

__global__ __launch_bounds__(256) void p3_csr(const int* __restrict__ part,
                                              const int* __restrict__ base,
                                              int* __restrict__ R, int* __restrict__ adj,
                                              float* __restrict__ dis, int N, int E) {
    __shared__ int hist[128];
    __shared__ int sc[128];
    __shared__ int cnt[128];
    int b = blockIdx.x;
    int n0 = b * 128;
    int nn = min(128, N - n0);
    int s = base[b], e = base[b + 1];
    int t = threadIdx.x;

    if (t < 128) hist[t] = 0;
    __syncthreads();
    for (int i = s + t; i < e; i += 256)
        atomicAdd(&hist[part[i] >> 17], 1);
    __syncthreads();

    if (t < 128) sc[t] = hist[t];
    __syncthreads();
    for (int off = 1; off < 128; off <<= 1) {
        int v = 0;
        if (t < 128 && t >= off) v = sc[t - off];
        __syncthreads();
        if (t < 128) sc[t] += v;
        __syncthreads();
    }
    if (t < 128) {
        int excl = sc[t] - hist[t];
        cnt[t] = excl;
        if (t < nn) {
            R[n0 + t] = s + excl;
            dis[n0 + t] = rsqrtf((float)hist[t] + 1.0f);   // +1 self-loop
        }
    }
    if (b == 0 && t == 0) R[N] = E;
    __syncthreads();

    for (int i = s + t; i < e; i += 256) {
        int p = part[i];
        int pos = atomicAdd(&cnt[p >> 17], 1);
        adj[s + pos] = p & 0x1FFFF;
    }
}

// ---------------- Y[n] = bf16((X[n] @ W) * dis[n]); W(f32) staged in LDS ----------------
// 4 nodes x 32 interleaved cols per thread. XBF16 selects bf16 vs f32 X rows.
// In-place safe for layer 2 (X == Y, both bf16): all X reads of this block's
// rows complete before the __syncthreads(); OOB clamp row (N-1) belongs to the
// clamping block itself, so no cross-block hazard.
template <bool XBF16>
__global__ __launch_bounds__(256, 2) void k_gemm_scale(
    const void* Xv, const float* __restrict__ W,
    const float* __restrict__ dis, unsigned short* Y, int N)
{
    __shared__ float Ws[EMB * EMB];   // 64 KB
    for (int i = threadIdx.x * 4; i < EMB * EMB; i += 256 * 4)
        *(float4*)&Ws[i] = *(const float4*)&W[i];
    __syncthreads();

    const int cg = threadIdx.x & 3;
    const int ns = threadIdx.x >> 2;
    const int base = blockIdx.x * 256;

    int n[4], nc[4];
#pragma unroll
    for (int i = 0; i < 4; ++i) {
        n[i] = base + ns + 64 * i;
        nc[i] = n[i] < N ? n[i] : (N - 1);
    }

    float4 acc[4][8];
#pragma unroll
    for (int i = 0; i < 4; ++i)
#pragma unroll
        for (int j = 0; j < 8; ++j) acc[i][j] = make_float4(0.f, 0.f, 0.f, 0.f);

#pragma unroll 1
    for (int k0 = 0; k0 < EMB; k0 += 8) {
        float a[4][8];
#pragma unroll
        for (int i = 0; i < 4; ++i) {
            if (XBF16) {
                uint4 u = *(const uint4*)((const unsigned short*)Xv + (size_t)nc[i] * EMB + k0);
                a[i][0] = bfu2f(u.x & 0xffffu); a[i][1] = bfu2f(u.x >> 16);
                a[i][2] = bfu2f(u.y & 0xffffu); a[i][3] = bfu2f(u.y >> 16);
                a[i][4] = bfu2f(u.z & 0xffffu); a[i][5] = bfu2f(u.z >> 16);
                a[i][6] = bfu2f(u.w & 0xffffu); a[i][7] = bfu2f(u.w >> 16);
            } else {
                const float4* xp = (const float4*)((const float*)Xv + (size_t)nc[i] * EMB + k0);
                float4 u0 = xp[0], u1 = xp[1];
                a[i][0]=u0.x; a[i][1]=u0.y; a[i][2]=u0.z; a[i][3]=u0.w;
                a[i][4]=u1.x; a[i][5]=u1.y; a[i][6]=u1.z; a[i][7]=u1.w;
            }
        }
#pragma unroll
        for (int kk = 0; kk < 8; ++kk) {
            const float* wr = &Ws[(k0 + kk) * EMB + cg * 4];
            float4 w[8];
#pragma unroll
            for (int j = 0; j < 8; ++j) w[j] = *(const float4*)(wr + j * 16);
#pragma unroll
            for (int i = 0; i < 4; ++i) {
                float av = a[i][kk];
#pragma unroll
                for (int j = 0; j < 8; ++j) {
                    acc[i][j].x += av * w[j].x;
                    acc[i][j].y += av * w[j].y;
                    acc[i][j].z += av * w[j].z;
                    acc[i][j].w += av * w[j].w;
                }
            }
        }
    }

    __syncthreads();   // in-place safety: all X reads complete before any Y write

#pragma unroll
    for (int i = 0; i < 4; ++i) {
        if (n[i] < N) {
            float dv = dis[n[i]];
            unsigned short* yr = Y + (size_t)n[i] * EMB + cg * 4;
#pragma unroll
            for (int j = 0; j < 8; ++j) {
                ushort4 o = { f2bf(acc[i][j].x * dv), f2bf(acc[i][j].y * dv),
                              f2bf(acc[i][j].z * dv), f2bf(acc[i][j].w * dv) };
                *(ushort4*)(yr + j * 16) = o;
            }
        }
    }
}

// ---------------- fused gather + normalize + bias (+relu) ----------------
// 32-lane group per node; lane covers 4 consecutive cols (8B bf16 loads).
// Out[n] = act(dis[n] * (Y[n] + sum_{e in CSR row n} Y[adj[e]]) + b)
template <bool RELU, bool BF16OUT>
__global__ __launch_bounds__(256) void k_gather_finalize(
    const int* __restrict__ R, const int* __restrict__ adj,
    const unsigned short* __restrict__ Y, const float* __restrict__ dis,
    const float* __restrict__ bias, void* __restrict__ Outv, int N)
{
    int t = blockIdx.x * 256 + threadIdx.x;
    int n = t >> 5;
    if (n >= N) return;
    int j = (t & 31) * 4;

    int rs = R[n], re = R[n + 1];

    float a0 = 0.f, a1 = 0.f, a2 = 0.f, a3 = 0.f;
    uint2 sv = *(const uint2*)(Y + (size_t)n * EMB + j);
    acc_bf4(sv, a0, a1, a2, a3);

    int e = rs;
    for (; e + 3 < re; e += 4) {
        int s0 = adj[e], s1 = adj[e + 1], s2 = adj[e + 2], s3 = adj[e + 3];
        uint2 v0 = *(const uint2*)(Y + (size_t)s0 * EMB + j);
        uint2 v1 = *(const uint2*)(Y + (size_t)s1 * EMB + j);
        uint2 v2 = *(const uint2*)(Y + (size_t)s2 * EMB + j);
        uint2 v3 = *(const uint2*)(Y + (size_t)s3 * EMB + j);
        acc_bf4(v0, a0, a1, a2, a3);
        acc_bf4(v1, a0, a1, a2, a3);
        acc_bf4(v2, a0, a1, a2, a3);
        acc_bf4(v3, a0, a1, a2, a3);
    }
    for (; e < re; ++e) {
        uint2 v0 = *(const uint2*)(Y + (size_t)adj[e] * EMB + j);
        acc_bf4(v0, a0, a1, a2, a3);
    }

    float dv = dis[n];
    float4 b = *(const float4*)(bias + j);
    float o0 = dv * a0 + b.x;
    float o1 = dv * a1 + b.y;
    float o2 = dv * a2 + b.z;
    float o3 = dv * a3 + b.w;
    if (RELU) {
        o0 = fmaxf(o0, 0.f); o1 = fmaxf(o1, 0.f);
        o2 = fmaxf(o2, 0.f); o3 = fmaxf(o3, 0.f);
    }
    if (BF16OUT) {
        ushort4 o = { f2bf(o0), f2bf(o1), f2bf(o2), f2bf(o3) };
        *(ushort4*)((unsigned short*)Outv + (size_t)n * EMB + j) = o;
    } else {
        float4 o = { o0, o1, o2, o3 };
        *(float4*)((float*)Outv + (size_t)n * EMB + j) = o;
    }
}

extern "C" void kernel_launch(void* const* d_in, const int* in_sizes, int n_in,
                              void* d_out, int out_size, void* d_ws, size_t ws_size,
                              hipStream_t stream) {
    const int* ei = (const int*)d_in[0];
    const int E = in_sizes[0] / 2;
    const float* emb = (const float*)d_in[2];
    const int N = in_sizes[2] / EMB;
    const float* W1 = (const float*)d_in[3];
    const float* b1 = (const float*)d_in[4];
    const float* W2 = (const float*)d_in[5];
    const float* b2 = (const float*)d_in[6];
    float* out = (float*)d_out;

    const int* src = ei;
    const int* dstp = ei + E;

    // Buffers:
    //   Y1b (bf16, 25.6 MB) = gemm1 out / gather1 in -> lives in d_out bytes
    //     (dead before gather2 writes d_out f32).
    //   Hb  (bf16, 25.6 MB, in ws) = gather1 out / gemm2 in & out (in-place)
    //     / gather2 in.  part[] + BH[] overlay Hb (dead before gather1).
    // ws total ~33 MB.
    char* w = (char*)d_ws;
    auto take = [&](size_t bytes) { char* p = w; w += (bytes + 511) & ~(size_t)511; return p; };
    float* dis  = (float*)take((size_t)N * 4);
    int*   R    = (int*)  take((size_t)(N + 1) * 4);
    int*   base = (int*)  take((size_t)(NBUC + 1) * 4);
    int*   tot  = (int*)  take((size_t)NBUC * 4);
    int*   adj  = (int*)  take((size_t)E * 4);
    unsigned short* Hb = (unsigned short*)take((size_t)N * EMB * 2);
    int*   part = (int*)Hb;                                  // overlay (dead before Hb)
    int*   BH   = (int*)((char*)Hb + (((size_t)E * 4 + 511) & ~(size_t)511));
    unsigned short* Y1b = (unsigned short*)d_out;            // overlay in d_out

    const int NB = (N + 127) / 128;
    const int chunk = (E + NPART - 1) / NPART;
    const int gN = (N + 255) / 256;
    const int gG = (N * 32 + 255) / 256;

    // --- CSR + dis build (shared by both layers) ---
    p1_hist   <<<NPART, 256, 0, stream>>>(dstp, BH, E, chunk);
    p_tot     <<<NBUC / 256, 256, 0, stream>>>(BH, tot);
    p_scan    <<<1, NBUC, 0, stream>>>(tot, base, E);
    p_offs    <<<NBUC / 256, 256, 0, stream>>>(BH, base);
    p2_scatter<<<NPART, 256, 0, stream>>>(src, dstp, BH, part, E, chunk);
    p3_csr    <<<NB, 256, 0, stream>>>(part, base, R, adj, dis, N, E);

    // --- layer 1: Y1b = bf16((emb@W1)*dis); Hb = bf16(relu(dis*(gather+self)+b1)) ---
    k_gemm_scale<false><<<gN, 256, 0, stream>>>(emb, W1, dis, Y1b, N);
    k_gather_finalize<true, true><<<gG, 256, 0, stream>>>(R, adj, Y1b, dis, b1, Hb, N);

    // --- layer 2: Hb = bf16((Hb@W2)*dis) in-place; out = dis*(gather+self)+b2 ---
    k_gemm_scale<true><<<gN, 256, 0, stream>>>(Hb, W2, dis, Hb, N);
    k_gather_finalize<false, false><<<gG, 256, 0, stream>>>(R, adj, Hb, dis, b2, out, N);
}

// Round 7
// 343.948 us; speedup vs baseline: 16.9144x; 1.2907x over previous
//
#include <hip/hip_runtime.h>

#define EMB 128
#define NBUC 1024          // coarse buckets: dst >> 7 (128 nodes per bucket)
#define NPART 256          // partition blocks for P1/P2

typedef __attribute__((ext_vector_type(8))) short short8;   // 8 bf16 (4 VGPRs)
typedef __attribute__((ext_vector_type(4))) float f32x4;    // MFMA acc

// ---------------- bf16 helpers ----------------
__device__ __forceinline__ unsigned short f2bf(float f) {
    union { float f; unsigned int i; } v; v.f = f;
    unsigned int x = v.i;
    x += 0x7fffu + ((x >> 16) & 1u);   // round-to-nearest-even
    return (unsigned short)(x >> 16);
}
__device__ __forceinline__ void acc_bf4(uint2 v, float& a0, float& a1, float& a2, float& a3) {
    union { unsigned int i; float f; } t;
    t.i = v.x << 16;          a0 += t.f;
    t.i = v.x & 0xffff0000u;  a1 += t.f;
    t.i = v.y << 16;          a2 += t.f;
    t.i = v.y & 0xffff0000u;  a3 += t.f;
}

// ============ CSR build: atomic-light two-level counting sort ============

__global__ __launch_bounds__(256) void p1_hist(const int* __restrict__ dst,
                                               int* __restrict__ BH, int E, int chunk) {
    __shared__ int h[NBUC];
    for (int i = threadIdx.x; i < NBUC; i += 256) h[i] = 0;
    __syncthreads();
    int s = blockIdx.x * chunk;
    int e = min(E, s + chunk);
    for (int i = s + threadIdx.x; i < e; i += 256)
        atomicAdd(&h[dst[i] >> 7], 1);
    __syncthreads();
    for (int i = threadIdx.x; i < NBUC; i += 256)
        BH[blockIdx.x * NBUC + i] = h[i];
}

__global__ __launch_bounds__(256) void p_tot(const int* __restrict__ BH,
                                             int* __restrict__ tot) {
    int b = blockIdx.x * 256 + threadIdx.x;
    int s = 0;
    for (int blk = 0; blk < NPART; ++blk) s += BH[blk * NBUC + b];
    tot[b] = s;
}

__global__ __launch_bounds__(1024) void p_scan(const int* __restrict__ tot,
                                               int* __restrict__ base, int E) {
    __shared__ int a[NBUC];
    int t = threadIdx.x;
    int v0 = tot[t];
    a[t] = v0;
    __syncthreads();
    for (int off = 1; off < NBUC; off <<= 1) {
        int v = (t >= off) ? a[t - off] : 0;
        __syncthreads();
        a[t] += v;
        __syncthreads();
    }
    base[t] = a[t] - v0;
    if (t == NBUC - 1) base[NBUC] = E;
}

__global__ __launch_bounds__(256) void p_offs(int* __restrict__ BH,
                                              const int* __restrict__ base) {
    int b = blockIdx.x * 256 + threadIdx.x;
    int run = base[b];
    for (int blk = 0; blk < NPART; ++blk) {
        int* p = &BH[blk * NBUC + b];
        int v = *p;
        *p = run;
        run += v;
    }
}

__global__ __launch_bounds__(256) void p2_scatter(const int* __restrict__ src,
                                                  const int* __restrict__ dst,
                                                  const int* __restrict__ BH,
                                                  int* __restrict__ part,
                                                  int E, int chunk) {
    __shared__ int cnt[NBUC];
    for (int i = threadIdx.x; i < NBUC; i += 256)
        cnt[i] = BH[blockIdx.x * NBUC + i];
    __syncthreads();
    int s = blockIdx.x * chunk;
    int e = min(E, s + chunk);
    for (int i = s + threadIdx.x; i < e; i += 256) {
        int d = dst[i];
        int pos = atomicAdd(&cnt[d >> 7], 1);
        part[pos] = src[i] | ((d & 127) << 17);   // src < 2^17, local node in [0,128)
    }
}

__global__ __launch_bounds__(256) void p3_csr(const int* __restrict__ part,
                                              const int* __restrict__ base,
                                              int* __restrict__ R, int* __restrict__ adj,
                                              float* __restrict__ dis, int N, int E) {
    __shared__ int hist[128];
    __shared__ int sc[128];
    __shared__ int cnt[128];
    int b = blockIdx.x;
    int n0 = b * 128;
    int nn = min(128, N - n0);
    int s = base[b], e = base[b + 1];
    int t = threadIdx.x;

    if (t < 128) hist[t] = 0;
    __syncthreads();
    for (int i = s + t; i < e; i += 256)
        atomicAdd(&hist[part[i] >> 17], 1);
    __syncthreads();

    if (t < 128) sc[t] = hist[t];
    __syncthreads();
    for (int off = 1; off < 128; off <<= 1) {
        int v = 0;
        if (t < 128 && t >= off) v = sc[t - off];
        __syncthreads();
        if (t < 128) sc[t] += v;
        __syncthreads();
    }
    if (t < 128) {
        int excl = sc[t] - hist[t];
        cnt[t] = excl;
        if (t < nn) {
            R[n0 + t] = s + excl;
            dis[n0 + t] = rsqrtf((float)hist[t] + 1.0f);   // +1 self-loop
        }
    }
    if (b == 0 && t == 0) R[N] = E;
    __syncthreads();

    for (int i = s + t; i < e; i += 256) {
        int p = part[i];
        int pos = atomicAdd(&cnt[p >> 17], 1);
        adj[s + pos] = p & 0x1FFFF;
    }
}

// ---------------- W pre-swizzle: f32 [128][128] -> bf16 fragment order ----------------
// Wb[kk][ct][q][nn][j] = W[kk*32 + q*8 + j][ct*16 + nn]; lane (q*16+nn) then reads
// its B-frag for (kk,ct) as one contiguous 16B short8 at index (kk*8+ct)*64 + lane.
__global__ __launch_bounds__(256) void k_prep_w(const float* __restrict__ W,
                                                unsigned short* __restrict__ Ws) {
    int idx = blockIdx.x * 256 + threadIdx.x;     // 64 blocks x 256 = 16384
    int k = idx >> 7, n = idx & 127;
    int kk = k >> 5, q = (k >> 3) & 3, j = k & 7;
    int ct = n >> 4, nn = n & 15;
    int didx = ((((kk * 8 + ct) * 4 + q) * 16 + nn) << 3) + j;
    Ws[didx] = f2bf(W[idx]);
}

// ---------------- MFMA GEMM: Y[n] = bf16((X[n] @ W) * dis[n]) ----------------
// 64 nodes/block, 16/wave; K=128 as 4 steps of mfma_f32_16x16x32_bf16.
// Fragment maps (doc-verified): A: m=lane&15, k=q*8+j; B: n=lane&15, k=q*8+j;
// D: n=lane&15, m=q*4+reg.
// In-place safe for layer 2 (X==Y): a block touches only its own 64 rows; all
// A-frag reads happen in the k-loop, before the __syncthreads() that precedes
// any store.  Epilogue round-trips through LDS for fully-coalesced stores.
template <bool XBF16>
__global__ __launch_bounds__(256) void k_gemm_mfma(
    const void* Xv, const unsigned short* __restrict__ Wsw,
    const float* __restrict__ dis, unsigned short* Y, int N)
{
    __shared__ __align__(16) unsigned short lds[16384];   // 32 KB: W frags, then out-stage

    // stage swizzled W (coalesced 16B copies)
    {
        const uint4* srcp = (const uint4*)Wsw;
        uint4* dstp = (uint4*)lds;
        for (int i = threadIdx.x; i < 2048; i += 256) dstp[i] = srcp[i];
    }
    __syncthreads();

    const int wave = threadIdx.x >> 6;
    const int lane = threadIdx.x & 63;
    const int q = lane >> 4, nn = lane & 15;
    const int row0 = blockIdx.x * 64 + wave * 16;
    const int arow = row0 + nn;
    const int arc = arow < N ? arow : N - 1;

    f32x4 acc[8];
#pragma unroll
    for (int ct = 0; ct < 8; ++ct) acc[ct] = (f32x4){0.f, 0.f, 0.f, 0.f};

#pragma unroll
    for (int kk = 0; kk < 4; ++kk) {
        short8 af;
        if (XBF16) {
            af = *(const short8*)((const unsigned short*)Xv + (size_t)arc * EMB + kk * 32 + q * 8);
        } else {
            const float* xp = (const float*)Xv + (size_t)arc * EMB + kk * 32 + q * 8;
            float4 u0 = *(const float4*)xp;
            float4 u1 = *(const float4*)(xp + 4);
            af[0] = (short)f2bf(u0.x); af[1] = (short)f2bf(u0.y);
            af[2] = (short)f2bf(u0.z); af[3] = (short)f2bf(u0.w);
            af[4] = (short)f2bf(u1.x); af[5] = (short)f2bf(u1.y);
            af[6] = (short)f2bf(u1.z); af[7] = (short)f2bf(u1.w);
        }
#pragma unroll
        for (int ct = 0; ct < 8; ++ct) {
            short8 bf = ((const short8*)lds)[(kk * 8 + ct) * 64 + lane];
            acc[ct] = __builtin_amdgcn_mfma_f32_16x16x32_bf16(af, bf, acc[ct], 0, 0, 0);
        }
    }

    __syncthreads();   // W reads + all A-frag (X) reads complete block-wide

    // scale by dis, pack bf16, stage to LDS (stride 136 shorts = 272B, 16B-aligned)
    float dv[4];
#pragma unroll
    for (int r = 0; r < 4; ++r) {
        int gm = row0 + q * 4 + r;
        dv[r] = dis[gm < N ? gm : N - 1];
    }
#pragma unroll
    for (int ct = 0; ct < 8; ++ct) {
#pragma unroll
        for (int r = 0; r < 4; ++r) {
            int ml = wave * 16 + q * 4 + r;
            lds[ml * 136 + ct * 16 + nn] = f2bf(acc[ct][r] * dv[r]);
        }
    }
    __syncthreads();

    // coalesced store: 64 rows x 256B, 16B per thread-item
    const int rbase = blockIdx.x * 64;
    for (int i = threadIdx.x; i < 1024; i += 256) {
        int row = i >> 4, off = i & 15;
        int grow = rbase + row;
        if (grow < N) {
            uint4 v = *(const uint4*)(lds + row * 136 + off * 8);
            *((uint4*)(Y + (size_t)grow * EMB) + off) = v;
        }
    }
}

// ---------------- fused gather + normalize + bias (+relu) ----------------
template <bool RELU, bool BF16OUT>
__global__ __launch_bounds__(256) void k_gather_finalize(
    const int* __restrict__ R, const int* __restrict__ adj,
    const unsigned short* __restrict__ Y, const float* __restrict__ dis,
    const float* __restrict__ bias, void* __restrict__ Outv, int N)
{
    int t = blockIdx.x * 256 + threadIdx.x;
    int n = t >> 5;
    if (n >= N) return;
    int j = (t & 31) * 4;

    int rs = R[n], re = R[n + 1];

    float a0 = 0.f, a1 = 0.f, a2 = 0.f, a3 = 0.f;
    uint2 sv = *(const uint2*)(Y + (size_t)n * EMB + j);
    acc_bf4(sv, a0, a1, a2, a3);

    int e = rs;
    for (; e + 3 < re; e += 4) {
        int s0 = adj[e], s1 = adj[e + 1], s2 = adj[e + 2], s3 = adj[e + 3];
        uint2 v0 = *(const uint2*)(Y + (size_t)s0 * EMB + j);
        uint2 v1 = *(const uint2*)(Y + (size_t)s1 * EMB + j);
        uint2 v2 = *(const uint2*)(Y + (size_t)s2 * EMB + j);
        uint2 v3 = *(const uint2*)(Y + (size_t)s3 * EMB + j);
        acc_bf4(v0, a0, a1, a2, a3);
        acc_bf4(v1, a0, a1, a2, a3);
        acc_bf4(v2, a0, a1, a2, a3);
        acc_bf4(v3, a0, a1, a2, a3);
    }
    for (; e < re; ++e) {
        uint2 v0 = *(const uint2*)(Y + (size_t)adj[e] * EMB + j);
        acc_bf4(v0, a0, a1, a2, a3);
    }

    float dv = dis[n];
    float4 b = *(const float4*)(bias + j);
    float o0 = dv * a0 + b.x;
    float o1 = dv * a1 + b.y;
    float o2 = dv * a2 + b.z;
    float o3 = dv * a3 + b.w;
    if (RELU) {
        o0 = fmaxf(o0, 0.f); o1 = fmaxf(o1, 0.f);
        o2 = fmaxf(o2, 0.f); o3 = fmaxf(o3, 0.f);
    }
    if (BF16OUT) {
        ushort4 o = { f2bf(o0), f2bf(o1), f2bf(o2), f2bf(o3) };
        *(ushort4*)((unsigned short*)Outv + (size_t)n * EMB + j) = o;
    } else {
        float4 o = { o0, o1, o2, o3 };
        *(float4*)((float*)Outv + (size_t)n * EMB + j) = o;
    }
}

extern "C" void kernel_launch(void* const* d_in, const int* in_sizes, int n_in,
                              void* d_out, int out_size, void* d_ws, size_t ws_size,
                              hipStream_t stream) {
    const int* ei = (const int*)d_in[0];
    const int E = in_sizes[0] / 2;
    const float* emb = (const float*)d_in[2];
    const int N = in_sizes[2] / EMB;
    const float* W1 = (const float*)d_in[3];
    const float* b1 = (const float*)d_in[4];
    const float* W2 = (const float*)d_in[5];
    const float* b2 = (const float*)d_in[6];
    float* out = (float*)d_out;

    const int* src = ei;
    const int* dstp = ei + E;

    // ws: dis | R | base | tot | adj | W1s | W2s | Hb (part/BH overlay Hb; both
    // dead before gather1 writes Hb).  Y1b lives in d_out bytes (dead before
    // gather2 writes d_out f32).  Total ~33 MB.
    char* w = (char*)d_ws;
    auto take = [&](size_t bytes) { char* p = w; w += (bytes + 511) & ~(size_t)511; return p; };
    float* dis  = (float*)take((size_t)N * 4);
    int*   R    = (int*)  take((size_t)(N + 1) * 4);
    int*   base = (int*)  take((size_t)(NBUC + 1) * 4);
    int*   tot  = (int*)  take((size_t)NBUC * 4);
    int*   adj  = (int*)  take((size_t)E * 4);
    unsigned short* W1s = (unsigned short*)take((size_t)EMB * EMB * 2);
    unsigned short* W2s = (unsigned short*)take((size_t)EMB * EMB * 2);
    unsigned short* Hb  = (unsigned short*)take((size_t)N * EMB * 2);
    int*   part = (int*)Hb;                                  // overlay (dead before Hb)
    int*   BH   = (int*)((char*)Hb + (((size_t)E * 4 + 511) & ~(size_t)511));
    unsigned short* Y1b = (unsigned short*)d_out;            // overlay in d_out

    const int NB = (N + 127) / 128;
    const int chunk = (E + NPART - 1) / NPART;
    const int gM = (N + 63) / 64;            // MFMA gemm blocks
    const int gG = (N * 32 + 255) / 256;

    // --- CSR + dis build (shared by both layers) ---
    p1_hist   <<<NPART, 256, 0, stream>>>(dstp, BH, E, chunk);
    p_tot     <<<NBUC / 256, 256, 0, stream>>>(BH, tot);
    p_scan    <<<1, NBUC, 0, stream>>>(tot, base, E);
    p_offs    <<<NBUC / 256, 256, 0, stream>>>(BH, base);
    p2_scatter<<<NPART, 256, 0, stream>>>(src, dstp, BH, part, E, chunk);
    p3_csr    <<<NB, 256, 0, stream>>>(part, base, R, adj, dis, N, E);

    // --- weight pre-swizzle (bf16 fragment order) ---
    k_prep_w<<<64, 256, 0, stream>>>(W1, W1s);
    k_prep_w<<<64, 256, 0, stream>>>(W2, W2s);

    // --- layer 1: Y1b = bf16((emb@W1)*dis); Hb = bf16(relu(dis*(gather+self)+b1)) ---
    k_gemm_mfma<false><<<gM, 256, 0, stream>>>(emb, W1s, dis, Y1b, N);
    k_gather_finalize<true, true><<<gG, 256, 0, stream>>>(R, adj, Y1b, dis, b1, Hb, N);

    // --- layer 2: Hb = bf16((Hb@W2)*dis) in-place; out = dis*(gather+self)+b2 ---
    k_gemm_mfma<true><<<gM, 256, 0, stream>>>(Hb, W2s, dis, Hb, N);
    k_gather_finalize<false, false><<<gG, 256, 0, stream>>>(R, adj, Hb, dis, b2, out, N);
}